// Round 8
// baseline (208.984 us; speedup 1.0000x reference)
//
#include <hip/hip_runtime.h>
#include <hip/hip_fp16.h>

#define NBINS 255
#define NPAIRS 32
#define BIGF 3.0e38f

// ws float-index layout (split path):
//  [0      ,16384 ) E   [64][256] fp32, tail BIGF
//  [16384  ,32768 ) PE
//  [32768  ,36864 ) ME  [64][16] float4 {e[4j+3]}
//  [36864  ,40960 ) MP
//  [40960  ,41984 ) CU  [64][16] coarse e[16j+15] (pad BIGF)
//  [41984  ,43008 ) CP
//  [43008  ,51200 ) W16 [64][256] fp16 PRE-SHIFTED
//  [51200  ,1099776) P  [4][262144] fp32 partial logits
//  [1099776,5294080) PW [16][262144] dwords (packed pair bins)
//  byte 21176320...: T16 [32][256][256] fp16 PRE-SHIFTED   (split: ws>=25370624)
//  byte 204800  ...: T16 (mono fallback: ws>=4399104)

__global__ void ebm_prep(const float* __restrict__ edges,
                         const float* __restrict__ pair_edges,
                         const float* __restrict__ w,
                         float* __restrict__ ws) {
    int tid = blockIdx.x * blockDim.x + threadIdx.x;  // 16384 threads
    int f = tid >> 8, j = tid & 255;
    float* E  = ws;
    float* PE = ws + 16384;
    float* ME = ws + 32768;
    float* MP = ws + 36864;
    float* CU = ws + 40960;
    float* CP = ws + 41984;
    __half* W = (__half*)(ws + 43008);
    E[tid]  = (j < NBINS) ? edges[f * NBINS + j]      : BIGF;
    PE[tid] = (j < NBINS) ? pair_edges[f * NBINS + j] : BIGF;
    int src = (j < 255) ? j + 1 : 0;
    W[tid]  = __float2half(w[f * 256 + src]);
    if (j < 64) {
        int idx = 4 * j + 3;
        ME[f * 64 + j] = (idx < NBINS) ? edges[f * NBINS + idx]      : BIGF;
        MP[f * 64 + j] = (idx < NBINS) ? pair_edges[f * NBINS + idx] : BIGF;
    }
    if (j < 16) {
        CU[f * 16 + j] = (j < 15) ? edges[f * NBINS + 16 * j + 15]      : BIGF;
        CP[f * 16 + j] = (j < 15) ? pair_edges[f * NBINS + 16 * j + 15] : BIGF;
    }
}

__global__ void ebm_prep_tables(const float* __restrict__ tables,
                                unsigned short* __restrict__ o) {
    int i = blockIdx.x * blockDim.x + threadIdx.x;    // 2097152 threads
    int b = i & 255, a = (i >> 8) & 255, p = i >> 16;
    int ra = (a < 255) ? a + 1 : 0;
    int rb = (b < 255) ? b + 1 : 0;
    o[i] = __half_as_ushort(__float2half(tables[(p << 16) + (ra << 8) + rb]));
}

// ============ split path: stage 1 — binning (quarter features / block) ======
__global__ __launch_bounds__(512, 8) void ebm_bins(
    const float* __restrict__ x,
    const int*   __restrict__ pairs,
    float* ws) {

    __shared__ float  sE[4096];     // 16 KB: quarter of E
    __shared__ float  sPE[4096];    // 16 KB
    __shared__ float4 sME[256];     // 4 KB
    __shared__ float4 sMP[256];     // 4 KB  -> 40960 B total

    int tid = threadIdx.x;
    int q  = blockIdx.x & 3;                    // feature quarter
    int row = (blockIdx.x >> 2) * 512 + tid;    // 2048 blocks -> 262144 rows
    int f0 = q * 16;

    const float4* w4 = (const float4*)ws;
    {
        float4* dE = (float4*)sE;
        float4* dP = (float4*)sPE;
        dE[tid]       = w4[f0 * 64 + tid];
        dE[tid + 512] = w4[f0 * 64 + tid + 512];
        dP[tid]       = w4[4096 + f0 * 64 + tid];
        dP[tid + 512] = w4[4096 + f0 * 64 + tid + 512];
        if (tid < 256) {
            sME[tid] = w4[8192 + f0 * 16 + tid];
            sMP[tid] = w4[9216 + f0 * 16 + tid];
        }
    }

    unsigned long long mask = 0;
#pragma unroll 1
    for (int k = 0; k < 2 * NPAIRS; ++k) mask |= 1ull << pairs[k];

    __syncthreads();

    const float*  CU = ws + 40960;
    const float*  CP = ws + 41984;
    const __half* Wg = (const __half*)(ws + 43008);
    const float4* sE4 = (const float4*)sE;
    const float4* sP4 = (const float4*)sPE;
    const float4* x4 = (const float4*)x + (size_t)row * 16;

    float acc = 0.f;
    unsigned pwq[4];

#pragma unroll
    for (int g = 0; g < 4; ++g) {
        float4 xg = x4[q * 4 + g];
        float xf[4] = {xg.x, xg.y, xg.z, xg.w};

        // ---- unary search, phase-wise over 4 features ----
        int t[4];
#pragma unroll
        for (int j = 0; j < 4; ++j) {
            const float* cu = CU + (f0 + 4 * g + j) * 16;   // uniform -> s_load
            int tt = 0;
#pragma unroll
            for (int k = 0; k < 15; ++k) tt += (xf[j] >= cu[k]);
            t[j] = tt;
        }
        float4 mu[4];
#pragma unroll
        for (int j = 0; j < 4; ++j) mu[j] = sME[(4 * g + j) * 16 + t[j]];
        int lo[4];
        float4 fu[4];
#pragma unroll
        for (int j = 0; j < 4; ++j) {
            int m = (xf[j] >= mu[j].x) + (xf[j] >= mu[j].y) + (xf[j] >= mu[j].z);
            lo[j] = 4 * t[j] + m;
            fu[j] = sE4[(4 * g + j) * 64 + lo[j]];
        }
#pragma unroll
        for (int j = 0; j < 4; ++j) {
            int c = 4 * lo[j] + (xf[j] >= fu[j].x) + (xf[j] >= fu[j].y) +
                    (xf[j] >= fu[j].z) + (xf[j] >= fu[j].w);
            acc += __half2float(Wg[(f0 + 4 * g + j) * 256 + c]);
        }

        // ---- pair search, per-feature, uniform skip when not in any pair ----
        unsigned pword = 0;
#pragma unroll
        for (int j = 0; j < 4; ++j) {
            int f = f0 + 4 * g + j;
            if ((mask >> f) & 1) {
                const float* cp = CP + f * 16;
                int tt = 0;
#pragma unroll
                for (int k = 0; k < 15; ++k) tt += (xf[j] >= cp[k]);
                float4 mp = sMP[(4 * g + j) * 16 + tt];
                int m = (xf[j] >= mp.x) + (xf[j] >= mp.y) + (xf[j] >= mp.z);
                int l2 = 4 * tt + m;
                float4 fp = sP4[(4 * g + j) * 64 + l2];
                int c2 = 4 * l2 + (xf[j] >= fp.x) + (xf[j] >= fp.y) +
                         (xf[j] >= fp.z) + (xf[j] >= fp.w);
                pword |= (unsigned)c2 << (8 * j);
            }
        }
        pwq[g] = pword;
    }

    float* P = ws + 51200;
    P[q * 262144 + row] = acc;                       // coalesced
    unsigned* PW = (unsigned*)(ws + 1099776);
#pragma unroll
    for (int g = 0; g < 4; ++g) PW[(q * 4 + g) * 262144 + row] = pwq[g];  // coalesced
}

// ============ split path: stage 2 — pair gathers + finalize =================
__global__ __launch_bounds__(256, 8) void ebm_pairs(
    const int*   __restrict__ pairs,
    const float* __restrict__ tables_f32,
    const float* __restrict__ bias,
    const float* __restrict__ ws,
    const __half* __restrict__ T16,
    int useT16,
    float* __restrict__ out) {

    __shared__ unsigned char sB[256 * 68];   // 68B stride: stride-17 dwords, 2-way max
    int tid = threadIdx.x;
    int row = blockIdx.x * 256 + tid;

    const float* P = ws + 51200;
    float acc = bias[0] + P[row] + P[262144 + row] + P[524288 + row] + P[786432 + row];

    const unsigned* PW = (const unsigned*)(ws + 1099776);
    unsigned* myw = (unsigned*)(sB + tid * 68);
#pragma unroll
    for (int k = 0; k < 16; ++k) myw[k] = PW[k * 262144 + row];   // coalesced reads

    const unsigned char* me = sB + tid * 68;
    if (useT16) {
#pragma unroll
        for (int p = 0; p < NPAIRS; ++p) {
            int a = pairs[2 * p], b = pairs[2 * p + 1];   // uniform
            int li = me[a], ri = me[b];                   // ds_read_u8
            acc += __half2float(T16[(p << 16) + (li << 8) + ri]);
        }
    } else {
#pragma unroll
        for (int p = 0; p < NPAIRS; ++p) {
            int a = pairs[2 * p], b = pairs[2 * p + 1];
            int li = me[a], ri = me[b];
            int lb = (li < 255) ? li + 1 : 0, rb = (ri < 255) ? ri + 1 : 0;
            acc += tables_f32[(p << 16) + (lb << 8) + rb];
        }
    }
    out[row] = 1.0f / (1.0f + __expf(-acc));
}

// ============ mono fallback (round-7 kernel) ================================
__device__ __forceinline__ unsigned pick16(const unsigned* pw, int s) {
    unsigned v01 = (s & 1) ? pw[1]  : pw[0];
    unsigned v23 = (s & 1) ? pw[3]  : pw[2];
    unsigned v45 = (s & 1) ? pw[5]  : pw[4];
    unsigned v67 = (s & 1) ? pw[7]  : pw[6];
    unsigned v89 = (s & 1) ? pw[9]  : pw[8];
    unsigned vab = (s & 1) ? pw[11] : pw[10];
    unsigned vcd = (s & 1) ? pw[13] : pw[12];
    unsigned vef = (s & 1) ? pw[15] : pw[14];
    unsigned w0 = (s & 2) ? v23 : v01;
    unsigned w1 = (s & 2) ? v67 : v45;
    unsigned w2 = (s & 2) ? vab : v89;
    unsigned w3 = (s & 2) ? vef : vcd;
    unsigned u0 = (s & 4) ? w1 : w0;
    unsigned u1 = (s & 4) ? w3 : w2;
    return (s & 8) ? u1 : u0;
}

__global__ __launch_bounds__(1024) void ebm_mono(
    const float* __restrict__ x,
    const int*   __restrict__ pairs,
    const float* __restrict__ tables_f32,
    const float* __restrict__ bias,
    const float* __restrict__ ws,
    const __half* __restrict__ T16,
    int useT16,
    float*       __restrict__ out) {

    __shared__ float  sE[16384];
    __shared__ float  sPE[16384];
    __shared__ float4 sME[1024];
    __shared__ float4 sMP[1024];

    int tid = threadIdx.x;
    {
        const float4* w4 = (const float4*)ws;
        float4* dE = (float4*)sE;
        float4* dP = (float4*)sPE;
        for (int i = tid; i < 4096; i += 1024) {
            dE[i] = w4[i];
            dP[i] = w4[4096 + i];
        }
        if (tid < 1024) {
            sME[tid] = w4[8192 + tid];
            sMP[tid] = w4[9216 + tid];
        }
    }
    const float*  CU = ws + 40960;
    const float*  CP = ws + 41984;
    const __half* Wg = (const __half*)(ws + 43008);
    float bias0 = bias[0];

    __syncthreads();

    int row = blockIdx.x * 1024 + tid;
    const float4* x4 = (const float4*)x + (size_t)row * 16;
    const float4* sE4 = (const float4*)sE;
    const float4* sP4 = (const float4*)sPE;

    float acc = 0.f;
    unsigned pw[16];

    float4 xg = x4[0];
#pragma unroll
    for (int g = 0; g < 16; ++g) {
        float4 xnext = xg;
        if (g < 15) xnext = x4[g + 1];
        float xf[4] = {xg.x, xg.y, xg.z, xg.w};
        int t[4];
#pragma unroll
        for (int j = 0; j < 4; ++j) {
            const float* cu = CU + (4 * g + j) * 16;
            int tt = 0;
#pragma unroll
            for (int k = 0; k < 15; ++k) tt += (xf[j] >= cu[k]);
            t[j] = tt;
        }
        int t2[4];
#pragma unroll
        for (int j = 0; j < 4; ++j) {
            const float* cp = CP + (4 * g + j) * 16;
            int tt = 0;
#pragma unroll
            for (int k = 0; k < 15; ++k) tt += (xf[j] >= cp[k]);
            t2[j] = tt;
        }
        float4 mu[4], mp[4];
#pragma unroll
        for (int j = 0; j < 4; ++j) mu[j] = sME[(4 * g + j) * 16 + t[j]];
#pragma unroll
        for (int j = 0; j < 4; ++j) mp[j] = sMP[(4 * g + j) * 16 + t2[j]];
        int lo[4], lo2[4];
        float4 fu[4], fp[4];
#pragma unroll
        for (int j = 0; j < 4; ++j) {
            int m = (xf[j] >= mu[j].x) + (xf[j] >= mu[j].y) + (xf[j] >= mu[j].z);
            lo[j] = 4 * t[j] + m;
            fu[j] = sE4[(4 * g + j) * 64 + lo[j]];
        }
#pragma unroll
        for (int j = 0; j < 4; ++j) {
            int m = (xf[j] >= mp[j].x) + (xf[j] >= mp[j].y) + (xf[j] >= mp[j].z);
            lo2[j] = 4 * t2[j] + m;
            fp[j] = sP4[(4 * g + j) * 64 + lo2[j]];
        }
#pragma unroll
        for (int j = 0; j < 4; ++j) {
            int c = 4 * lo[j] + (xf[j] >= fu[j].x) + (xf[j] >= fu[j].y) +
                    (xf[j] >= fu[j].z) + (xf[j] >= fu[j].w);
            acc += __half2float(Wg[(4 * g + j) * 256 + c]);
        }
        unsigned pword = 0;
#pragma unroll
        for (int j = 0; j < 4; ++j) {
            int c2 = 4 * lo2[j] + (xf[j] >= fp[j].x) + (xf[j] >= fp[j].y) +
                     (xf[j] >= fp[j].z) + (xf[j] >= fp[j].w);
            pword |= (unsigned)c2 << (8 * j);
        }
        pw[g] = pword;
        xg = xnext;
    }

    if (useT16) {
#pragma unroll
        for (int p = 0; p < NPAIRS; ++p) {
            int a = pairs[2 * p], b = pairs[2 * p + 1];
            unsigned wa = pick16(pw, a >> 2);
            unsigned wb = pick16(pw, b >> 2);
            int li = (wa >> ((a & 3) * 8)) & 255;
            int ri = (wb >> ((b & 3) * 8)) & 255;
            acc += __half2float(T16[(p << 16) + (li << 8) + ri]);
        }
    } else {
#pragma unroll
        for (int p = 0; p < NPAIRS; ++p) {
            int a = pairs[2 * p], b = pairs[2 * p + 1];
            unsigned wa = pick16(pw, a >> 2);
            unsigned wb = pick16(pw, b >> 2);
            int li = (wa >> ((a & 3) * 8)) & 255;
            int ri = (wb >> ((b & 3) * 8)) & 255;
            int lb = (li < 255) ? li + 1 : 0;
            int rb = (ri < 255) ? ri + 1 : 0;
            acc += tables_f32[(p << 16) + (lb << 8) + rb];
        }
    }
    out[row] = 1.0f / (1.0f + __expf(-(acc + bias0)));
}

extern "C" void kernel_launch(void* const* d_in, const int* in_sizes, int n_in,
                              void* d_out, int out_size, void* d_ws, size_t ws_size,
                              hipStream_t stream) {
    const float* x          = (const float*)d_in[0];
    const float* edges      = (const float*)d_in[1];
    const float* w          = (const float*)d_in[2];
    const float* pair_edges = (const float*)d_in[3];
    const int*   pairs      = (const int*)d_in[4];
    const float* tables     = (const float*)d_in[5];
    const float* bias       = (const float*)d_in[6];
    float* out = (float*)d_out;
    float* ws  = (float*)d_ws;

    ebm_prep<<<64, 256, 0, stream>>>(edges, pair_edges, w, ws);

    if (ws_size >= (size_t)21176320) {
        // split path
        int useT16 = (ws_size >= (size_t)25370624) ? 1 : 0;
        __half* T16 = (__half*)((char*)d_ws + 21176320);
        if (useT16) {
            ebm_prep_tables<<<2048, 1024, 0, stream>>>(tables, (unsigned short*)T16);
        }
        ebm_bins<<<2048, 512, 0, stream>>>(x, pairs, ws);
        ebm_pairs<<<1024, 256, 0, stream>>>(pairs, tables, bias, ws, T16, useT16, out);
    } else {
        // mono fallback (round-7 structure)
        int useT16 = (ws_size >= (size_t)4399104) ? 1 : 0;
        __half* T16 = (__half*)((char*)d_ws + 204800);
        if (useT16) {
            ebm_prep_tables<<<2048, 1024, 0, stream>>>(tables, (unsigned short*)T16);
        }
        ebm_mono<<<256, 1024, 0, stream>>>(x, pairs, tables, bias, ws, T16, useT16, out);
    }
}